// Round 1
// baseline (153.709 us; speedup 1.0000x reference)
//
#include <hip/hip_runtime.h>

#define D_FEAT 128
#define H1 18
#define H2 32
#define EPS 1e-8f

__global__ __launch_bounds__(256) void edge_encoder_kernel(
    const float* __restrict__ x,
    const int* __restrict__ edge_index,
    const float* __restrict__ edge_attr,
    const float* __restrict__ W1,   // [5,18]
    const float* __restrict__ b1,   // [18]
    const float* __restrict__ W2,   // [18,32]
    const float* __restrict__ b2,   // [32]
    float* __restrict__ out,        // [E,32]
    int n_edges)
{
    __shared__ float sW1[5 * H1];
    __shared__ float sb1[H1];
    __shared__ float sW2[H1 * H2];
    __shared__ float sb2[H2];

    for (int i = threadIdx.x; i < 5 * H1; i += blockDim.x) sW1[i] = W1[i];
    for (int i = threadIdx.x; i < H1; i += blockDim.x) sb1[i] = b1[i];
    for (int i = threadIdx.x; i < H1 * H2; i += blockDim.x) sW2[i] = W2[i];
    for (int i = threadIdx.x; i < H2; i += blockDim.x) sb2[i] = b2[i];
    __syncthreads();

    const int lane = threadIdx.x & 63;
    const int sub = lane & 31;       // lane within 32-lane edge-group
    const int base = lane & 32;      // group base within wave
    const int wavesPerBlock = blockDim.x >> 6;
    const int waveId = blockIdx.x * wavesPerBlock + (threadIdx.x >> 6);
    const int totalWaves = gridDim.x * wavesPerBlock;

    for (long long g = waveId; 2 * g < (long long)n_edges; g += totalWaves) {
        const long long e = 2 * g + (lane >> 5);
        const bool active = (e < (long long)n_edges);

        float dot = 0.f, ss = 0.f, tt = 0.f;
        float4 ea = make_float4(0.f, 0.f, 0.f, 0.f);

        if (active) {
            const int srcN = edge_index[e];
            const int tgtN = edge_index[(long long)n_edges + e];
            const float4 s4 = *reinterpret_cast<const float4*>(
                x + (size_t)srcN * D_FEAT + (size_t)sub * 4);
            const float4 t4 = *reinterpret_cast<const float4*>(
                x + (size_t)tgtN * D_FEAT + (size_t)sub * 4);
            dot = s4.x * t4.x + s4.y * t4.y + s4.z * t4.z + s4.w * t4.w;
            ss  = s4.x * s4.x + s4.y * s4.y + s4.z * s4.z + s4.w * s4.w;
            tt  = t4.x * t4.x + t4.y * t4.y + t4.z * t4.z + t4.w * t4.w;
            ea = *reinterpret_cast<const float4*>(edge_attr + e * 4);
        }

        // 32-lane butterfly reduction (xor masks < 32 stay within the group)
        #pragma unroll
        for (int m = 16; m >= 1; m >>= 1) {
            dot += __shfl_xor(dot, m);
            ss  += __shfl_xor(ss, m);
            tt  += __shfl_xor(tt, m);
        }

        const float ns = fmaxf(sqrtf(ss), EPS);
        const float nt = fmaxf(sqrtf(tt), EPS);
        const float cosv = dot / (ns * nt);

        const float f[5] = { ea.x, ea.y, ea.z, ea.w, cosv };

        // layer 1: lanes 0..17 of each group compute one hidden unit
        float hval = 0.f;
        if (sub < H1) {
            hval = sb1[sub];
            #pragma unroll
            for (int k = 0; k < 5; ++k)
                hval = fmaf(f[k], sW1[k * H1 + sub], hval);
            hval = fmaxf(hval, 0.f);
        }

        // layer 2: each lane computes one of 32 outputs
        float acc = sb2[sub];
        #pragma unroll
        for (int i = 0; i < H1; ++i) {
            const float hi = __shfl(hval, base + i);
            acc = fmaf(hi, sW2[i * H2 + sub], acc);
        }
        acc = fmaxf(acc, 0.f);

        if (active) out[e * H2 + sub] = acc;
    }
}

extern "C" void kernel_launch(void* const* d_in, const int* in_sizes, int n_in,
                              void* d_out, int out_size, void* d_ws, size_t ws_size,
                              hipStream_t stream) {
    const float* x         = (const float*)d_in[0];
    const int*   edge_idx  = (const int*)d_in[1];
    const float* edge_attr = (const float*)d_in[2];
    const float* W1        = (const float*)d_in[3];
    const float* b1        = (const float*)d_in[4];
    const float* W2        = (const float*)d_in[5];
    const float* b2        = (const float*)d_in[6];
    float* out = (float*)d_out;

    const int n_edges = in_sizes[1] / 2;  // edge_index is [2, E]

    const int block = 256;
    const int grid = 2048;
    edge_encoder_kernel<<<grid, block, 0, stream>>>(
        x, edge_idx, edge_attr, W1, b1, W2, b2, out, n_edges);
}

// Round 2
// 124.538 us; speedup vs baseline: 1.2342x; 1.2342x over previous
//
#include <hip/hip_runtime.h>
#include <stdint.h>

#define D_FEAT 128
#define H1 18
#define H2 32
#define EPS 1e-8f

__device__ __forceinline__ uint32_t f32_to_bf16_rne(float f) {
    uint32_t u = __float_as_uint(f);
    return (u + 0x7fffu + ((u >> 16) & 1u)) >> 16;
}
__device__ __forceinline__ float bf16lo(uint32_t v) { return __uint_as_float(v << 16); }
__device__ __forceinline__ float bf16hi(uint32_t v) { return __uint_as_float(v & 0xffff0000u); }

// ---------- pre-pass: x[f32,N,128] -> packed bf16 [N,64 u32] + inv-norm [N] ----------
__global__ __launch_bounds__(256) void prep_kernel(
    const float* __restrict__ x,
    uint32_t* __restrict__ xb,
    float* __restrict__ invn,
    int n_nodes)
{
    const int lane = threadIdx.x & 63;
    const int wavesPerBlock = blockDim.x >> 6;
    const int totalWaves = gridDim.x * wavesPerBlock;
    for (int node = blockIdx.x * wavesPerBlock + (threadIdx.x >> 6);
         node < n_nodes; node += totalWaves) {
        const float2 v = *reinterpret_cast<const float2*>(
            x + (size_t)node * D_FEAT + lane * 2);
        float ss = v.x * v.x + v.y * v.y;
        xb[(size_t)node * 64 + lane] =
            (f32_to_bf16_rne(v.y) << 16) | f32_to_bf16_rne(v.x);
        #pragma unroll
        for (int m = 32; m >= 1; m >>= 1) ss += __shfl_xor(ss, m);
        if (lane == 0) invn[node] = 1.0f / fmaxf(sqrtf(ss), EPS);
    }
}

// ---------- tiny-MLP helper: one 32-lane group handles one edge ----------
__device__ __forceinline__ float mlp_out(
    const float4 ea, float cosv,
    const float* __restrict__ sW1, const float* __restrict__ sb1,
    const float* __restrict__ sW2, const float* __restrict__ sb2,
    int sub, int base)
{
    const float f[5] = { ea.x, ea.y, ea.z, ea.w, cosv };
    float hval = 0.f;
    if (sub < H1) {
        hval = sb1[sub];
        #pragma unroll
        for (int k = 0; k < 5; ++k) hval = fmaf(f[k], sW1[k * H1 + sub], hval);
        hval = fmaxf(hval, 0.f);
    }
    float acc = sb2[sub];
    #pragma unroll
    for (int i = 0; i < H1; ++i)
        acc = fmaf(__shfl(hval, base + i), sW2[i * H2 + sub], acc);
    return fmaxf(acc, 0.f);
}

// ---------- main: bf16 gathers + inv-norm table, 4 edges per wave-iter ----------
__global__ __launch_bounds__(256) void edge_kernel_bf16(
    const uint2* __restrict__ xb,       // [N, 32] (4 bf16 per uint2)
    const float* __restrict__ invn,     // [N]
    const int* __restrict__ edge_index, // [2, E]
    const float4* __restrict__ edge_attr,
    const float* __restrict__ W1, const float* __restrict__ b1,
    const float* __restrict__ W2, const float* __restrict__ b2,
    float* __restrict__ out, int n_edges)
{
    __shared__ float sW1[5 * H1];
    __shared__ float sb1[H1];
    __shared__ float sW2[H1 * H2];
    __shared__ float sb2[H2];
    for (int i = threadIdx.x; i < 5 * H1; i += blockDim.x) sW1[i] = W1[i];
    for (int i = threadIdx.x; i < H1; i += blockDim.x) sb1[i] = b1[i];
    for (int i = threadIdx.x; i < H1 * H2; i += blockDim.x) sW2[i] = W2[i];
    for (int i = threadIdx.x; i < H2; i += blockDim.x) sb2[i] = b2[i];
    __syncthreads();

    const int lane = threadIdx.x & 63;
    const int sub = lane & 31;
    const int base = lane & 32;
    const int half = lane >> 5;
    const int wavesPerBlock = blockDim.x >> 6;
    const long long waveId = (long long)blockIdx.x * wavesPerBlock + (threadIdx.x >> 6);
    const long long totalWaves = (long long)gridDim.x * wavesPerBlock;

    for (long long g = waveId; 4 * g < (long long)n_edges; g += totalWaves) {
        const long long eA = 4 * g + half;
        const long long eB = eA + 2;
        const bool actA = eA < (long long)n_edges;
        const bool actB = eB < (long long)n_edges;

        uint2 sA = make_uint2(0, 0), tA = make_uint2(0, 0);
        uint2 sB = make_uint2(0, 0), tB = make_uint2(0, 0);
        float4 eaA = make_float4(0.f, 0.f, 0.f, 0.f);
        float4 eaB = make_float4(0.f, 0.f, 0.f, 0.f);
        float invA = 0.f, invB = 0.f;

        if (actA) {
            const int srcA = edge_index[eA];
            const int tgtA = edge_index[(long long)n_edges + eA];
            sA = xb[(size_t)srcA * 32 + sub];
            tA = xb[(size_t)tgtA * 32 + sub];
            eaA = edge_attr[eA];
            invA = invn[srcA] * invn[tgtA];
        }
        if (actB) {
            const int srcB = edge_index[eB];
            const int tgtB = edge_index[(long long)n_edges + eB];
            sB = xb[(size_t)srcB * 32 + sub];
            tB = xb[(size_t)tgtB * 32 + sub];
            eaB = edge_attr[eB];
            invB = invn[srcB] * invn[tgtB];
        }

        float dotA = bf16lo(sA.x) * bf16lo(tA.x) + bf16hi(sA.x) * bf16hi(tA.x)
                   + bf16lo(sA.y) * bf16lo(tA.y) + bf16hi(sA.y) * bf16hi(tA.y);
        float dotB = bf16lo(sB.x) * bf16lo(tB.x) + bf16hi(sB.x) * bf16hi(tB.x)
                   + bf16lo(sB.y) * bf16lo(tB.y) + bf16hi(sB.y) * bf16hi(tB.y);

        #pragma unroll
        for (int m = 16; m >= 1; m >>= 1) {
            dotA += __shfl_xor(dotA, m);
            dotB += __shfl_xor(dotB, m);
        }
        const float cosA = dotA * invA;
        const float cosB = dotB * invB;

        const float oA = mlp_out(eaA, cosA, sW1, sb1, sW2, sb2, sub, base);
        const float oB = mlp_out(eaB, cosB, sW1, sb1, sW2, sb2, sub, base);

        if (actA) out[eA * H2 + sub] = oA;
        if (actB) out[eB * H2 + sub] = oB;
    }
}

// ---------- fallback (fp32 direct, known-good from round 1) ----------
__global__ __launch_bounds__(256) void edge_encoder_fp32(
    const float* __restrict__ x,
    const int* __restrict__ edge_index,
    const float* __restrict__ edge_attr,
    const float* __restrict__ W1, const float* __restrict__ b1,
    const float* __restrict__ W2, const float* __restrict__ b2,
    float* __restrict__ out, int n_edges)
{
    __shared__ float sW1[5 * H1];
    __shared__ float sb1[H1];
    __shared__ float sW2[H1 * H2];
    __shared__ float sb2[H2];
    for (int i = threadIdx.x; i < 5 * H1; i += blockDim.x) sW1[i] = W1[i];
    for (int i = threadIdx.x; i < H1; i += blockDim.x) sb1[i] = b1[i];
    for (int i = threadIdx.x; i < H1 * H2; i += blockDim.x) sW2[i] = W2[i];
    for (int i = threadIdx.x; i < H2; i += blockDim.x) sb2[i] = b2[i];
    __syncthreads();

    const int lane = threadIdx.x & 63;
    const int sub = lane & 31;
    const int base = lane & 32;
    const int wavesPerBlock = blockDim.x >> 6;
    const int waveId = blockIdx.x * wavesPerBlock + (threadIdx.x >> 6);
    const int totalWaves = gridDim.x * wavesPerBlock;

    for (long long g = waveId; 2 * g < (long long)n_edges; g += totalWaves) {
        const long long e = 2 * g + (lane >> 5);
        const bool active = (e < (long long)n_edges);
        float dot = 0.f, ss = 0.f, tt = 0.f;
        float4 ea = make_float4(0.f, 0.f, 0.f, 0.f);
        if (active) {
            const int srcN = edge_index[e];
            const int tgtN = edge_index[(long long)n_edges + e];
            const float4 s4 = *reinterpret_cast<const float4*>(
                x + (size_t)srcN * D_FEAT + (size_t)sub * 4);
            const float4 t4 = *reinterpret_cast<const float4*>(
                x + (size_t)tgtN * D_FEAT + (size_t)sub * 4);
            dot = s4.x * t4.x + s4.y * t4.y + s4.z * t4.z + s4.w * t4.w;
            ss  = s4.x * s4.x + s4.y * s4.y + s4.z * s4.z + s4.w * s4.w;
            tt  = t4.x * t4.x + t4.y * t4.y + t4.z * t4.z + t4.w * t4.w;
            ea = *reinterpret_cast<const float4*>(edge_attr + e * 4);
        }
        #pragma unroll
        for (int m = 16; m >= 1; m >>= 1) {
            dot += __shfl_xor(dot, m);
            ss  += __shfl_xor(ss, m);
            tt  += __shfl_xor(tt, m);
        }
        const float cosv = dot / (fmaxf(sqrtf(ss), EPS) * fmaxf(sqrtf(tt), EPS));
        const float o = mlp_out(ea, cosv, sW1, sb1, sW2, sb2, sub, base);
        if (active) out[e * H2 + sub] = o;
    }
}

extern "C" void kernel_launch(void* const* d_in, const int* in_sizes, int n_in,
                              void* d_out, int out_size, void* d_ws, size_t ws_size,
                              hipStream_t stream) {
    const float* x         = (const float*)d_in[0];
    const int*   edge_idx  = (const int*)d_in[1];
    const float* edge_attr = (const float*)d_in[2];
    const float* W1        = (const float*)d_in[3];
    const float* b1        = (const float*)d_in[4];
    const float* W2        = (const float*)d_in[5];
    const float* b2        = (const float*)d_in[6];
    float* out = (float*)d_out;

    const int n_nodes = in_sizes[0] / D_FEAT;
    const int n_edges = in_sizes[1] / 2;

    const size_t xb_bytes = (size_t)n_nodes * (D_FEAT / 2) * sizeof(uint32_t);
    const size_t need = xb_bytes + (size_t)n_nodes * sizeof(float);

    if (ws_size >= need) {
        uint32_t* xb = (uint32_t*)d_ws;
        float* invn = (float*)((char*)d_ws + xb_bytes);

        const int block = 256;
        const int prep_grid = (n_nodes + 3) / 4;   // one wave per node
        prep_kernel<<<prep_grid, block, 0, stream>>>(x, xb, invn, n_nodes);

        edge_kernel_bf16<<<2048, block, 0, stream>>>(
            (const uint2*)xb, invn, edge_idx, (const float4*)edge_attr,
            W1, b1, W2, b2, out, n_edges);
    } else {
        edge_encoder_fp32<<<2048, 256, 0, stream>>>(
            x, edge_idx, edge_attr, W1, b1, W2, b2, out, n_edges);
    }
}

// Round 3
// 86.395 us; speedup vs baseline: 1.7791x; 1.4415x over previous
//
#include <hip/hip_runtime.h>
#include <stdint.h>

#define D_FEAT 128
#define H1 18
#define H2 32
#define EPS 1e-8f

__device__ __forceinline__ uint32_t f32_to_bf16_rne(float f) {
    uint32_t u = __float_as_uint(f);
    return (u + 0x7fffu + ((u >> 16) & 1u)) >> 16;
}
__device__ __forceinline__ float bf16lo(uint32_t v) { return __uint_as_float(v << 16); }
__device__ __forceinline__ float bf16hi(uint32_t v) { return __uint_as_float(v & 0xffff0000u); }

__device__ __forceinline__ float dot8(uint4 s, uint4 t) {
    float d;
    d  = bf16lo(s.x) * bf16lo(t.x);
    d  = fmaf(bf16hi(s.x), bf16hi(t.x), d);
    d  = fmaf(bf16lo(s.y), bf16lo(t.y), d);
    d  = fmaf(bf16hi(s.y), bf16hi(t.y), d);
    d  = fmaf(bf16lo(s.z), bf16lo(t.z), d);
    d  = fmaf(bf16hi(s.z), bf16hi(t.z), d);
    d  = fmaf(bf16lo(s.w), bf16lo(t.w), d);
    d  = fmaf(bf16hi(s.w), bf16hi(t.w), d);
    return d;
}

// ---------- prep: x[f32,N,128] -> NORMALIZED packed bf16 [N,32 uint2] ----------
// 2 nodes per wave (32 lanes each), float4 loads, 5-step butterfly.
__global__ __launch_bounds__(256) void prep_kernel(
    const float* __restrict__ x,
    uint2* __restrict__ xb,      // [N][32] : 4 bf16 per uint2
    int n_nodes)
{
    const int lane = threadIdx.x & 63;
    const int sub = lane & 31;
    const int half = lane >> 5;
    const int wavesPerBlock = blockDim.x >> 6;
    const long long wv = (long long)blockIdx.x * wavesPerBlock + (threadIdx.x >> 6);
    const int node = (int)(2 * wv + half);
    if (node >= n_nodes) return;

    const float4 v = *reinterpret_cast<const float4*>(
        x + (size_t)node * D_FEAT + (size_t)sub * 4);
    float ss = v.x * v.x + v.y * v.y + v.z * v.z + v.w * v.w;
    #pragma unroll
    for (int m = 16; m >= 1; m >>= 1) ss += __shfl_xor(ss, m);
    const float r = 1.0f / fmaxf(sqrtf(ss), EPS);
    uint2 p;
    p.x = (f32_to_bf16_rne(v.y * r) << 16) | f32_to_bf16_rne(v.x * r);
    p.y = (f32_to_bf16_rne(v.w * r) << 16) | f32_to_bf16_rne(v.z * r);
    xb[(size_t)node * 32 + sub] = p;
}

// ---------- main: 64-edge bursts per wave ----------
// Phase 0: lane=edge loads indices+attr, stages indices to per-wave LDS.
// Phase 1: 16 steps; 4 x 16-lane groups gather normalized bf16 rows (uint4),
//          per-lane partial dot + 4-step butterfly, lane k==0 writes dot to LDS.
// Phase 2: lane=edge reads its cos, computes full 5->18->32 MLP in registers
//          (weights via wave-uniform s_loads), 8 x float4 coalesced-ish stores.
__global__ __launch_bounds__(256) void edge_kernel(
    const uint4* __restrict__ xb,       // [N][16] (8 bf16 per uint4)
    const int* __restrict__ edge_index, // [2, E]
    const float4* __restrict__ edge_attr,
    const float* __restrict__ W1, const float* __restrict__ b1,
    const float* __restrict__ W2, const float* __restrict__ b2,
    float* __restrict__ out, int n_edges)
{
    __shared__ int sIdx[4][64];
    __shared__ int tIdx[4][64];
    __shared__ float dotb[4][64];

    const int lane = threadIdx.x & 63;
    const int w = threadIdx.x >> 6;   // wave slot (blockDim=256 -> 4 waves)
    const int g = lane >> 4;          // 16-lane group 0..3
    const int k = lane & 15;          // lane within group
    const long long waveId = (long long)blockIdx.x * 4 + w;
    const long long totalWaves = (long long)gridDim.x * 4;
    const long long nBursts = ((long long)n_edges + 63) >> 6;

    for (long long burst = waveId; burst < nBursts; burst += totalWaves) {
        const long long e = (burst << 6) + lane;
        const bool act = e < (long long)n_edges;

        int srcL = 0, tgtL = 0;
        float4 attr = make_float4(0.f, 0.f, 0.f, 0.f);
        if (act) {
            srcL = edge_index[e];
            tgtL = edge_index[(long long)n_edges + e];
            attr = edge_attr[e];
        }
        sIdx[w][lane] = srcL;
        tIdx[w][lane] = tgtL;

        #pragma unroll 4
        for (int step = 0; step < 16; ++step) {
            const int eg = step * 4 + g;
            const int sN = sIdx[w][eg];
            const int tN = tIdx[w][eg];
            const uint4 su = xb[(size_t)sN * 16 + k];
            const uint4 tu = xb[(size_t)tN * 16 + k];
            float d = dot8(su, tu);
            d += __shfl_xor(d, 1);
            d += __shfl_xor(d, 2);
            d += __shfl_xor(d, 4);
            d += __shfl_xor(d, 8);
            if (k == 0) dotb[w][eg] = d;
        }

        const float cosv = dotb[w][lane];

        // ---- per-lane MLP: feats = {attr.xyzw, cosv} ----
        float h[H1];
        #pragma unroll
        for (int i = 0; i < H1; ++i) {
            float v = b1[i];
            v = fmaf(attr.x, W1[0 * H1 + i], v);
            v = fmaf(attr.y, W1[1 * H1 + i], v);
            v = fmaf(attr.z, W1[2 * H1 + i], v);
            v = fmaf(attr.w, W1[3 * H1 + i], v);
            v = fmaf(cosv,   W1[4 * H1 + i], v);
            h[i] = fmaxf(v, 0.f);
        }

        const float4* __restrict__ W2v = reinterpret_cast<const float4*>(W2);
        const float4* __restrict__ b2v = reinterpret_cast<const float4*>(b2);
        if (act) {
            float* op = out + (size_t)e * H2;
            #pragma unroll
            for (int jg = 0; jg < 8; ++jg) {
                float4 a = b2v[jg];
                #pragma unroll
                for (int i = 0; i < H1; ++i) {
                    const float4 wv = W2v[i * 8 + jg];
                    a.x = fmaf(h[i], wv.x, a.x);
                    a.y = fmaf(h[i], wv.y, a.y);
                    a.z = fmaf(h[i], wv.z, a.z);
                    a.w = fmaf(h[i], wv.w, a.w);
                }
                a.x = fmaxf(a.x, 0.f);
                a.y = fmaxf(a.y, 0.f);
                a.z = fmaxf(a.z, 0.f);
                a.w = fmaxf(a.w, 0.f);
                *reinterpret_cast<float4*>(op + jg * 4) = a;
            }
        }
    }
}

// ---------- fallback (fp32 direct, known-good from round 1) ----------
__device__ __forceinline__ float mlp_out32(
    const float4 ea, float cosv,
    const float* __restrict__ sW1, const float* __restrict__ sb1,
    const float* __restrict__ sW2, const float* __restrict__ sb2,
    int sub, int base)
{
    const float f[5] = { ea.x, ea.y, ea.z, ea.w, cosv };
    float hval = 0.f;
    if (sub < H1) {
        hval = sb1[sub];
        #pragma unroll
        for (int kk = 0; kk < 5; ++kk) hval = fmaf(f[kk], sW1[kk * H1 + sub], hval);
        hval = fmaxf(hval, 0.f);
    }
    float acc = sb2[sub];
    #pragma unroll
    for (int i = 0; i < H1; ++i)
        acc = fmaf(__shfl(hval, base + i), sW2[i * H2 + sub], acc);
    return fmaxf(acc, 0.f);
}

__global__ __launch_bounds__(256) void edge_encoder_fp32(
    const float* __restrict__ x,
    const int* __restrict__ edge_index,
    const float* __restrict__ edge_attr,
    const float* __restrict__ W1, const float* __restrict__ b1,
    const float* __restrict__ W2, const float* __restrict__ b2,
    float* __restrict__ out, int n_edges)
{
    __shared__ float sW1[5 * H1];
    __shared__ float sb1[H1];
    __shared__ float sW2[H1 * H2];
    __shared__ float sb2[H2];
    for (int i = threadIdx.x; i < 5 * H1; i += blockDim.x) sW1[i] = W1[i];
    for (int i = threadIdx.x; i < H1; i += blockDim.x) sb1[i] = b1[i];
    for (int i = threadIdx.x; i < H1 * H2; i += blockDim.x) sW2[i] = W2[i];
    for (int i = threadIdx.x; i < H2; i += blockDim.x) sb2[i] = b2[i];
    __syncthreads();

    const int lane = threadIdx.x & 63;
    const int sub = lane & 31;
    const int base = lane & 32;
    const int wavesPerBlock = blockDim.x >> 6;
    const int waveId = blockIdx.x * wavesPerBlock + (threadIdx.x >> 6);
    const int totalWaves = gridDim.x * wavesPerBlock;

    for (long long gg = waveId; 2 * gg < (long long)n_edges; gg += totalWaves) {
        const long long e = 2 * gg + (lane >> 5);
        const bool active = (e < (long long)n_edges);
        float dot = 0.f, ss = 0.f, tt = 0.f;
        float4 ea = make_float4(0.f, 0.f, 0.f, 0.f);
        if (active) {
            const int srcN = edge_index[e];
            const int tgtN = edge_index[(long long)n_edges + e];
            const float4 s4 = *reinterpret_cast<const float4*>(
                x + (size_t)srcN * D_FEAT + (size_t)sub * 4);
            const float4 t4 = *reinterpret_cast<const float4*>(
                x + (size_t)tgtN * D_FEAT + (size_t)sub * 4);
            dot = s4.x * t4.x + s4.y * t4.y + s4.z * t4.z + s4.w * t4.w;
            ss  = s4.x * s4.x + s4.y * s4.y + s4.z * s4.z + s4.w * s4.w;
            tt  = t4.x * t4.x + t4.y * t4.y + t4.z * t4.z + t4.w * t4.w;
            ea = *reinterpret_cast<const float4*>(edge_attr + e * 4);
        }
        #pragma unroll
        for (int m = 16; m >= 1; m >>= 1) {
            dot += __shfl_xor(dot, m);
            ss  += __shfl_xor(ss, m);
            tt  += __shfl_xor(tt, m);
        }
        const float cosv = dot / (fmaxf(sqrtf(ss), EPS) * fmaxf(sqrtf(tt), EPS));
        const float o = mlp_out32(ea, cosv, sW1, sb1, sW2, sb2, sub, base);
        if (active) out[e * H2 + sub] = o;
    }
}

extern "C" void kernel_launch(void* const* d_in, const int* in_sizes, int n_in,
                              void* d_out, int out_size, void* d_ws, size_t ws_size,
                              hipStream_t stream) {
    const float* x         = (const float*)d_in[0];
    const int*   edge_idx  = (const int*)d_in[1];
    const float* edge_attr = (const float*)d_in[2];
    const float* W1        = (const float*)d_in[3];
    const float* b1        = (const float*)d_in[4];
    const float* W2        = (const float*)d_in[5];
    const float* b2        = (const float*)d_in[6];
    float* out = (float*)d_out;

    const int n_nodes = in_sizes[0] / D_FEAT;
    const int n_edges = in_sizes[1] / 2;

    const size_t xb_bytes = (size_t)n_nodes * (D_FEAT / 2) * sizeof(uint32_t);

    if (ws_size >= xb_bytes) {
        uint2* xb = (uint2*)d_ws;
        const int block = 256;
        // prep: 2 nodes per wave, 8 nodes per block
        const int prep_grid = (n_nodes + 7) / 8;
        prep_kernel<<<prep_grid, block, 0, stream>>>(x, xb, n_nodes);

        edge_kernel<<<2048, block, 0, stream>>>(
            (const uint4*)xb, edge_idx, (const float4*)edge_attr,
            W1, b1, W2, b2, out, n_edges);
    } else {
        edge_encoder_fp32<<<2048, 256, 0, stream>>>(
            x, edge_idx, edge_attr, W1, b1, W2, b2, out, n_edges);
    }
}

// Round 4
// 78.439 us; speedup vs baseline: 1.9596x; 1.1014x over previous
//
#include <hip/hip_runtime.h>
#include <stdint.h>

#define D_FEAT 128
#define H1 18
#define H2 32
#define EPS 1e-8f

__device__ __forceinline__ uint32_t f32_to_bf16_rne(float f) {
    uint32_t u = __float_as_uint(f);
    return (u + 0x7fffu + ((u >> 16) & 1u)) >> 16;
}
__device__ __forceinline__ float bf16lo(uint32_t v) { return __uint_as_float(v << 16); }
__device__ __forceinline__ float bf16hi(uint32_t v) { return __uint_as_float(v & 0xffff0000u); }

__device__ __forceinline__ float dot8(uint4 s, uint4 t) {
    float d;
    d  = bf16lo(s.x) * bf16lo(t.x);
    d  = fmaf(bf16hi(s.x), bf16hi(t.x), d);
    d  = fmaf(bf16lo(s.y), bf16lo(t.y), d);
    d  = fmaf(bf16hi(s.y), bf16hi(t.y), d);
    d  = fmaf(bf16lo(s.z), bf16lo(t.z), d);
    d  = fmaf(bf16hi(s.z), bf16hi(t.z), d);
    d  = fmaf(bf16lo(s.w), bf16lo(t.w), d);
    d  = fmaf(bf16hi(s.w), bf16hi(t.w), d);
    return d;
}

// ---------- prep: x[f32,N,128] -> NORMALIZED packed bf16 [N,32 uint2] ----------
__global__ __launch_bounds__(256) void prep_kernel(
    const float* __restrict__ x,
    uint2* __restrict__ xb,      // [N][32] : 4 bf16 per uint2
    int n_nodes)
{
    const int lane = threadIdx.x & 63;
    const int sub = lane & 31;
    const int half = lane >> 5;
    const int wavesPerBlock = blockDim.x >> 6;
    const long long wv = (long long)blockIdx.x * wavesPerBlock + (threadIdx.x >> 6);
    const int node = (int)(2 * wv + half);
    if (node >= n_nodes) return;

    const float4 v = *reinterpret_cast<const float4*>(
        x + (size_t)node * D_FEAT + (size_t)sub * 4);
    float ss = v.x * v.x + v.y * v.y + v.z * v.z + v.w * v.w;
    #pragma unroll
    for (int m = 16; m >= 1; m >>= 1) ss += __shfl_xor(ss, m);
    const float r = 1.0f / fmaxf(sqrtf(ss), EPS);
    uint2 p;
    p.x = (f32_to_bf16_rne(v.y * r) << 16) | f32_to_bf16_rne(v.x * r);
    p.y = (f32_to_bf16_rne(v.w * r) << 16) | f32_to_bf16_rne(v.z * r);
    xb[(size_t)node * 32 + sub] = p;
}

// ---------- main: exactly ONE 64-edge burst per wave ----------
// Phase 0: lane=edge loads indices+attr, stages indices to per-wave LDS.
// Phase 1: issue ALL 32 gathers (16 steps x {src,tgt}) into registers,
//          then consume: per-step dot8 + 4-step butterfly -> dot to LDS.
// Phase 2: lane=edge computes full 5->18->32 MLP in registers, float4 stores.
__global__ __launch_bounds__(256, 3) void edge_kernel(
    const uint4* __restrict__ xb,       // [N][16] (8 bf16 per uint4)
    const int* __restrict__ edge_index, // [2, E]
    const float4* __restrict__ edge_attr,
    const float* __restrict__ W1, const float* __restrict__ b1,
    const float* __restrict__ W2, const float* __restrict__ b2,
    float* __restrict__ out, int n_edges)
{
    __shared__ int sIdx[4][64];
    __shared__ int tIdx[4][64];
    __shared__ float dotb[4][64];

    const int lane = threadIdx.x & 63;
    const int w = threadIdx.x >> 6;   // wave slot (blockDim=256 -> 4 waves)
    const int g = lane >> 4;          // 16-lane group 0..3
    const int k = lane & 15;          // lane within group
    const long long burst = (long long)blockIdx.x * 4 + w;
    const long long nBursts = ((long long)n_edges + 63) >> 6;
    if (burst >= nBursts) return;

    const long long e = (burst << 6) + lane;
    const bool act = e < (long long)n_edges;

    int srcL = 0, tgtL = 0;
    float4 attr = make_float4(0.f, 0.f, 0.f, 0.f);
    if (act) {
        srcL = edge_index[e];
        tgtL = edge_index[(long long)n_edges + e];
        attr = edge_attr[e];
    }
    sIdx[w][lane] = srcL;
    tIdx[w][lane] = tgtL;

    // ---- issue all 32 independent gathers (static-indexed register arrays) ----
    uint4 su[16], tu[16];
    #pragma unroll
    for (int s = 0; s < 16; ++s) {
        const int eg = s * 4 + g;
        su[s] = xb[(size_t)sIdx[w][eg] * 16 + k];
        tu[s] = xb[(size_t)tIdx[w][eg] * 16 + k];
    }

    // ---- consume ----
    #pragma unroll
    for (int s = 0; s < 16; ++s) {
        const int eg = s * 4 + g;
        float d = dot8(su[s], tu[s]);
        d += __shfl_xor(d, 1);
        d += __shfl_xor(d, 2);
        d += __shfl_xor(d, 4);
        d += __shfl_xor(d, 8);
        if (k == 0) dotb[w][eg] = d;
    }

    const float cosv = dotb[w][lane];

    // ---- per-lane MLP: feats = {attr.xyzw, cosv} ----
    float h[H1];
    #pragma unroll
    for (int i = 0; i < H1; ++i) {
        float v = b1[i];
        v = fmaf(attr.x, W1[0 * H1 + i], v);
        v = fmaf(attr.y, W1[1 * H1 + i], v);
        v = fmaf(attr.z, W1[2 * H1 + i], v);
        v = fmaf(attr.w, W1[3 * H1 + i], v);
        v = fmaf(cosv,   W1[4 * H1 + i], v);
        h[i] = fmaxf(v, 0.f);
    }

    const float4* __restrict__ W2v = reinterpret_cast<const float4*>(W2);
    const float4* __restrict__ b2v = reinterpret_cast<const float4*>(b2);
    if (act) {
        float* op = out + (size_t)e * H2;
        #pragma unroll
        for (int jg = 0; jg < 8; ++jg) {
            float4 a = b2v[jg];
            #pragma unroll
            for (int i = 0; i < H1; ++i) {
                const float4 wv = W2v[i * 8 + jg];
                a.x = fmaf(h[i], wv.x, a.x);
                a.y = fmaf(h[i], wv.y, a.y);
                a.z = fmaf(h[i], wv.z, a.z);
                a.w = fmaf(h[i], wv.w, a.w);
            }
            a.x = fmaxf(a.x, 0.f);
            a.y = fmaxf(a.y, 0.f);
            a.z = fmaxf(a.z, 0.f);
            a.w = fmaxf(a.w, 0.f);
            *reinterpret_cast<float4*>(op + jg * 4) = a;
        }
    }
}

// ---------- fallback (fp32 direct, known-good from round 1) ----------
__device__ __forceinline__ float mlp_out32(
    const float4 ea, float cosv,
    const float* __restrict__ sW1, const float* __restrict__ sb1,
    const float* __restrict__ sW2, const float* __restrict__ sb2,
    int sub, int base)
{
    const float f[5] = { ea.x, ea.y, ea.z, ea.w, cosv };
    float hval = 0.f;
    if (sub < H1) {
        hval = sb1[sub];
        #pragma unroll
        for (int kk = 0; kk < 5; ++kk) hval = fmaf(f[kk], sW1[kk * H1 + sub], hval);
        hval = fmaxf(hval, 0.f);
    }
    float acc = sb2[sub];
    #pragma unroll
    for (int i = 0; i < H1; ++i)
        acc = fmaf(__shfl(hval, base + i), sW2[i * H2 + sub], acc);
    return fmaxf(acc, 0.f);
}

__global__ __launch_bounds__(256) void edge_encoder_fp32(
    const float* __restrict__ x,
    const int* __restrict__ edge_index,
    const float* __restrict__ edge_attr,
    const float* __restrict__ W1, const float* __restrict__ b1,
    const float* __restrict__ W2, const float* __restrict__ b2,
    float* __restrict__ out, int n_edges)
{
    __shared__ float sW1[5 * H1];
    __shared__ float sb1[H1];
    __shared__ float sW2[H1 * H2];
    __shared__ float sb2[H2];
    for (int i = threadIdx.x; i < 5 * H1; i += blockDim.x) sW1[i] = W1[i];
    for (int i = threadIdx.x; i < H1; i += blockDim.x) sb1[i] = b1[i];
    for (int i = threadIdx.x; i < H1 * H2; i += blockDim.x) sW2[i] = W2[i];
    for (int i = threadIdx.x; i < H2; i += blockDim.x) sb2[i] = b2[i];
    __syncthreads();

    const int lane = threadIdx.x & 63;
    const int sub = lane & 31;
    const int base = lane & 32;
    const int wavesPerBlock = blockDim.x >> 6;
    const int waveId = blockIdx.x * wavesPerBlock + (threadIdx.x >> 6);
    const int totalWaves = gridDim.x * wavesPerBlock;

    for (long long gg = waveId; 2 * gg < (long long)n_edges; gg += totalWaves) {
        const long long e = 2 * gg + (lane >> 5);
        const bool active = (e < (long long)n_edges);
        float dot = 0.f, ss = 0.f, tt = 0.f;
        float4 ea = make_float4(0.f, 0.f, 0.f, 0.f);
        if (active) {
            const int srcN = edge_index[e];
            const int tgtN = edge_index[(long long)n_edges + e];
            const float4 s4 = *reinterpret_cast<const float4*>(
                x + (size_t)srcN * D_FEAT + (size_t)sub * 4);
            const float4 t4 = *reinterpret_cast<const float4*>(
                x + (size_t)tgtN * D_FEAT + (size_t)sub * 4);
            dot = s4.x * t4.x + s4.y * t4.y + s4.z * t4.z + s4.w * t4.w;
            ss  = s4.x * s4.x + s4.y * s4.y + s4.z * s4.z + s4.w * s4.w;
            tt  = t4.x * t4.x + t4.y * t4.y + t4.z * t4.z + t4.w * t4.w;
            ea = *reinterpret_cast<const float4*>(edge_attr + e * 4);
        }
        #pragma unroll
        for (int m = 16; m >= 1; m >>= 1) {
            dot += __shfl_xor(dot, m);
            ss  += __shfl_xor(ss, m);
            tt  += __shfl_xor(tt, m);
        }
        const float cosv = dot / (fmaxf(sqrtf(ss), EPS) * fmaxf(sqrtf(tt), EPS));
        const float o = mlp_out32(ea, cosv, sW1, sb1, sW2, sb2, sub, base);
        if (active) out[e * H2 + sub] = o;
    }
}

extern "C" void kernel_launch(void* const* d_in, const int* in_sizes, int n_in,
                              void* d_out, int out_size, void* d_ws, size_t ws_size,
                              hipStream_t stream) {
    const float* x         = (const float*)d_in[0];
    const int*   edge_idx  = (const int*)d_in[1];
    const float* edge_attr = (const float*)d_in[2];
    const float* W1        = (const float*)d_in[3];
    const float* b1        = (const float*)d_in[4];
    const float* W2        = (const float*)d_in[5];
    const float* b2        = (const float*)d_in[6];
    float* out = (float*)d_out;

    const int n_nodes = in_sizes[0] / D_FEAT;
    const int n_edges = in_sizes[1] / 2;

    const size_t xb_bytes = (size_t)n_nodes * (D_FEAT / 2) * sizeof(uint32_t);

    if (ws_size >= xb_bytes) {
        uint2* xb = (uint2*)d_ws;
        const int block = 256;
        const int prep_grid = (n_nodes + 7) / 8;   // 2 nodes/wave, 8/block
        prep_kernel<<<prep_grid, block, 0, stream>>>(x, xb, n_nodes);

        const long long nBursts = ((long long)n_edges + 63) >> 6;
        const int grid = (int)((nBursts + 3) / 4);  // exactly one burst per wave
        edge_kernel<<<grid, block, 0, stream>>>(
            (const uint4*)xb, edge_idx, (const float4*)edge_attr,
            W1, b1, W2, b2, out, n_edges);
    } else {
        edge_encoder_fp32<<<2048, 256, 0, stream>>>(
            x, edge_idx, edge_attr, W1, b1, W2, b2, out, n_edges);
    }
}